// Round 1
// baseline (529.454 us; speedup 1.0000x reference)
//
#include <hip/hip_runtime.h>
#include <hip/hip_fp16.h>

typedef _Float16 f16;
typedef __attribute__((ext_vector_type(4))) _Float16 f16x4;
typedef __attribute__((ext_vector_type(8))) _Float16 f16x8;
typedef __attribute__((ext_vector_type(4))) float f32x4;

#define MFMA_F16(a,b,c) __builtin_amdgcn_mfma_f32_16x16x32_f16((a),(b),(c),0,0,0)

// ---------------------------------------------------------------------------
// GEMM: out[M,N] = A[M,K] @ W[N,K]^T + bias  (torch Linear convention)
// A: fp32 or fp16 (A_F16), W: fp32, out: fp16 or fp32 (OUT_F32).
// BM=BN=128, BK=32, 256 threads = 4 waves in 2x2, each wave 64x64 via 4x4
// tiles of mfma_f32_16x16x32_f16.
// ---------------------------------------------------------------------------
template<bool A_F16, bool OUT_F32>
__global__ __launch_bounds__(256) void gemm_tn(const void* __restrict__ Ap,
                                               const float* __restrict__ W,
                                               const float* __restrict__ bias,
                                               void* __restrict__ outp,
                                               int M, int N, int Kd) {
  constexpr int BM = 128, BN = 128, BK = 32, PAD = 40;  // 40*2=80B rows, 16B aligned
  __shared__ f16 As[BM][PAD];
  __shared__ f16 Bs[BN][PAD];
  const int tid  = threadIdx.x;
  const int lane = tid & 63;
  const int wid  = tid >> 6;
  const int col  = lane & 15;
  const int quad = lane >> 4;
  const int wm = (wid >> 1) * 64, wn = (wid & 1) * 64;
  const int m0 = blockIdx.x * BM, n0 = blockIdx.y * BN;

  f32x4 acc[4][4];
#pragma unroll
  for (int i = 0; i < 4; i++)
#pragma unroll
    for (int j = 0; j < 4; j++) acc[i][j] = (f32x4){0.f, 0.f, 0.f, 0.f};

  const int kIters = Kd / BK;
  for (int kt = 0; kt < kIters; ++kt) {
    const int k0 = kt * BK;
    if constexpr (A_F16) {
      const f16* A = (const f16*)Ap;
#pragma unroll
      for (int i = 0; i < 2; i++) {
        int f = i * 256 + tid;
        int r = f >> 2, ch = f & 3;
        f16x8 v = *(const f16x8*)(A + (size_t)(m0 + r) * Kd + k0 + ch * 8);
        *(f16x8*)&As[r][ch * 8] = v;
      }
    } else {
      const float* A = (const float*)Ap;
#pragma unroll
      for (int i = 0; i < 4; i++) {
        int f = i * 256 + tid;
        int r = f >> 3, c4 = f & 7;
        float4 v = *(const float4*)(A + (size_t)(m0 + r) * Kd + k0 + c4 * 4);
        f16x4 hh;
        hh[0] = (f16)v.x; hh[1] = (f16)v.y; hh[2] = (f16)v.z; hh[3] = (f16)v.w;
        *(f16x4*)&As[r][c4 * 4] = hh;
      }
    }
#pragma unroll
    for (int i = 0; i < 4; i++) {
      int f = i * 256 + tid;
      int r = f >> 3, c4 = f & 7;
      float4 v = *(const float4*)(W + (size_t)(n0 + r) * Kd + k0 + c4 * 4);
      f16x4 hh;
      hh[0] = (f16)v.x; hh[1] = (f16)v.y; hh[2] = (f16)v.z; hh[3] = (f16)v.w;
      *(f16x4*)&Bs[r][c4 * 4] = hh;
    }
    __syncthreads();
    f16x8 af[4], bf[4];
#pragma unroll
    for (int i = 0; i < 4; i++) af[i] = *(const f16x8*)&As[wm + i * 16 + col][quad * 8];
#pragma unroll
    for (int j = 0; j < 4; j++) bf[j] = *(const f16x8*)&Bs[wn + j * 16 + col][quad * 8];
#pragma unroll
    for (int i = 0; i < 4; i++)
#pragma unroll
      for (int j = 0; j < 4; j++) acc[i][j] = MFMA_F16(af[i], bf[j], acc[i][j]);
    __syncthreads();
  }

  // Epilogue: C/D layout col=lane&15, row=quad*4+reg
#pragma unroll
  for (int j = 0; j < 4; j++) {
    const int c = n0 + wn + j * 16 + col;
    const float bv = bias ? bias[c] : 0.0f;
#pragma unroll
    for (int i = 0; i < 4; i++) {
      const int r0 = m0 + wm + i * 16 + quad * 4;
#pragma unroll
      for (int r = 0; r < 4; r++) {
        float val = acc[i][j][r] + bv;
        if constexpr (OUT_F32)
          ((float*)outp)[(size_t)(r0 + r) * N + c] = val;
        else
          ((f16*)outp)[(size_t)(r0 + r) * N + c] = (f16)val;
      }
    }
  }
}

// ---------------------------------------------------------------------------
// Fused flash-style attention per (b,h): O = softmax(Q K^T / sqrt(128) + B) V
// grid (n1/128, b*h) = (8, 128), 256 threads = 4 waves, each wave owns 32
// query rows. K/V tiles of 128 staged in LDS (V transposed -> Vs[c][n]);
// P goes C-layout -> LDS -> A-layout (m120 pattern). Online softmax in fp32.
// ---------------------------------------------------------------------------
__global__ __launch_bounds__(256, 1) void attn_fused(const f16* __restrict__ Q,
                                                     const f16* __restrict__ K,
                                                     const f16* __restrict__ V,
                                                     const float* __restrict__ Bm,
                                                     f16* __restrict__ O) {
  constexpr int D = 128, BN = 128, BM = 128, SEQ = 1024, PAD = 136;  // 272B rows
  __shared__ f16 Ks[BN][PAD];
  __shared__ f16 Vs[D][PAD];   // transposed: Vs[c][n]
  __shared__ f16 Ps[BM][PAD];  // per-wave rows, no cross-wave hazard
  const int tid  = threadIdx.x;
  const int lane = tid & 63;
  const int wid  = tid >> 6;
  const int col  = lane & 15;
  const int quad = lane >> 4;
  const int bh = blockIdx.y, b = bh >> 3, h = bh & 7;
  const int m0 = blockIdx.x * BM;
  const int wm = wid * 32;

  const f16* Qb = Q + ((size_t)(b * SEQ + m0 + wm)) * 1024 + h * D;
  const f16* Kb = K + ((size_t)(b * SEQ)) * 1024 + h * D;
  const f16* Vb = V + ((size_t)(b * SEQ)) * 1024 + h * D;

  // Q fragments (A-layout): row = lane&15, k = quad*8+j
  f16x8 qf[2][4];
#pragma unroll
  for (int i = 0; i < 2; i++)
#pragma unroll
    for (int ks = 0; ks < 4; ks++)
      qf[i][ks] = *(const f16x8*)(Qb + (size_t)(i * 16 + col) * 1024 + ks * 32 + quad * 8);

  float m_i[2][4], l_i[2][4];
  f32x4 oacc[2][8];
#pragma unroll
  for (int i = 0; i < 2; i++)
#pragma unroll
    for (int r = 0; r < 4; r++) { m_i[i][r] = -1e30f; l_i[i][r] = 0.f; }
#pragma unroll
  for (int i = 0; i < 2; i++)
#pragma unroll
    for (int ct = 0; ct < 8; ct++) oacc[i][ct] = (f32x4){0.f, 0.f, 0.f, 0.f};

  const float scale = 0.0883883476483184f;  // 1/sqrt(128)

  for (int t = 0; t < SEQ / BN; ++t) {
    const int n0 = t * BN;
    // stage K tile [BN][D], k-contiguous
#pragma unroll
    for (int i = 0; i < 8; i++) {
      int f = i * 256 + tid;
      int r = f >> 4, ch = f & 15;
      *(f16x8*)&Ks[r][ch * 8] = *(const f16x8*)(Kb + (size_t)(n0 + r) * 1024 + ch * 8);
    }
    // stage V transposed: lane-per-row reads keep LDS writes conflict-free
    {
      int n = tid & 127;
      int cb = (tid >> 7) * 8;
#pragma unroll
      for (int i = 0; i < 8; i++) {
        int c0 = (cb + i) * 8;
        f16x8 v = *(const f16x8*)(Vb + (size_t)(n0 + n) * 1024 + c0);
#pragma unroll
        for (int j = 0; j < 8; j++) Vs[c0 + j][n] = v[j];
      }
    }
    __syncthreads();

    // S = Q K^T  (wave's 32 rows x 128 cols)
    f32x4 s[2][8];
#pragma unroll
    for (int i = 0; i < 2; i++)
#pragma unroll
      for (int jt = 0; jt < 8; jt++) s[i][jt] = (f32x4){0.f, 0.f, 0.f, 0.f};
#pragma unroll
    for (int ks = 0; ks < 4; ks++) {
      f16x8 kf[8];
#pragma unroll
      for (int jt = 0; jt < 8; jt++)
        kf[jt] = *(const f16x8*)&Ks[jt * 16 + col][ks * 32 + quad * 8];
#pragma unroll
      for (int i = 0; i < 2; i++)
#pragma unroll
        for (int jt = 0; jt < 8; jt++) s[i][jt] = MFMA_F16(qf[i][ks], kf[jt], s[i][jt]);
    }

    // scale + additive bias B[m, n] (fp32)
    const float* Bp = Bm + (size_t)(m0 + wm) * SEQ + n0;
#pragma unroll
    for (int i = 0; i < 2; i++)
#pragma unroll
      for (int r = 0; r < 4; r++) {
        const float* Brow = Bp + (size_t)(i * 16 + quad * 4 + r) * SEQ;
#pragma unroll
        for (int jt = 0; jt < 8; jt++)
          s[i][jt][r] = s[i][jt][r] * scale + Brow[jt * 16 + col];
      }

    // online softmax (row stats across the 16 lanes sharing a row)
#pragma unroll
    for (int i = 0; i < 2; i++)
#pragma unroll
      for (int r = 0; r < 4; r++) {
        float mx = -1e30f;
#pragma unroll
        for (int jt = 0; jt < 8; jt++) mx = fmaxf(mx, s[i][jt][r]);
#pragma unroll
        for (int d = 1; d < 16; d <<= 1) mx = fmaxf(mx, __shfl_xor(mx, d));
        float mnew = fmaxf(m_i[i][r], mx);
        float alpha = __expf(m_i[i][r] - mnew);
        float rsum = 0.f;
#pragma unroll
        for (int jt = 0; jt < 8; jt++) {
          float p = __expf(s[i][jt][r] - mnew);
          s[i][jt][r] = p;
          rsum += p;
        }
#pragma unroll
        for (int d = 1; d < 16; d <<= 1) rsum += __shfl_xor(rsum, d);
        m_i[i][r] = mnew;
        l_i[i][r] = l_i[i][r] * alpha + rsum;
#pragma unroll
        for (int ct = 0; ct < 8; ct++) oacc[i][ct][r] *= alpha;
      }

    // P: C-layout regs -> LDS (own rows only)
#pragma unroll
    for (int i = 0; i < 2; i++)
#pragma unroll
      for (int jt = 0; jt < 8; jt++)
#pragma unroll
        for (int r = 0; r < 4; r++)
          Ps[wm + i * 16 + quad * 4 + r][jt * 16 + col] = (f16)s[i][jt][r];

    // O += P @ V
#pragma unroll
    for (int ks = 0; ks < 4; ks++) {
      f16x8 pf[2];
#pragma unroll
      for (int i = 0; i < 2; i++)
        pf[i] = *(const f16x8*)&Ps[wm + i * 16 + col][ks * 32 + quad * 8];
      f16x8 vf[8];
#pragma unroll
      for (int ct = 0; ct < 8; ct++)
        vf[ct] = *(const f16x8*)&Vs[ct * 16 + col][ks * 32 + quad * 8];
#pragma unroll
      for (int i = 0; i < 2; i++)
#pragma unroll
        for (int ct = 0; ct < 8; ct++)
          oacc[i][ct] = MFMA_F16(pf[i], vf[ct], oacc[i][ct]);
    }
    __syncthreads();
  }

  // epilogue: O / l -> fp16 workspace
  f16* Ob = O + ((size_t)(b * SEQ + m0 + wm)) * 1024 + h * D;
#pragma unroll
  for (int i = 0; i < 2; i++)
#pragma unroll
    for (int r = 0; r < 4; r++) {
      const float inv = 1.0f / l_i[i][r];
#pragma unroll
      for (int ct = 0; ct < 8; ct++)
        Ob[(size_t)(i * 16 + quad * 4 + r) * 1024 + ct * 16 + col] =
            (f16)(oacc[i][ct][r] * inv);
    }
}

extern "C" void kernel_launch(void* const* d_in, const int* in_sizes, int n_in,
                              void* d_out, int out_size, void* d_ws, size_t ws_size,
                              hipStream_t stream) {
  (void)in_sizes; (void)n_in; (void)out_size; (void)ws_size;
  const float* x1  = (const float*)d_in[0];   // [16,1024,256]
  const float* x2  = (const float*)d_in[1];   // [16,1024,256]
  const float* Bm  = (const float*)d_in[2];   // [1024,1024]
  const float* wq  = (const float*)d_in[3];
  const float* wqb = (const float*)d_in[4];
  const float* wk  = (const float*)d_in[5];
  const float* wkb = (const float*)d_in[6];
  const float* wv  = (const float*)d_in[7];
  const float* wvb = (const float*)d_in[8];
  const float* pw  = (const float*)d_in[9];   // [128,1024]
  const float* pb  = (const float*)d_in[10];  // [128]
  float* out = (float*)d_out;                 // [16,1024,128] fp32

  const size_t ELEMS = (size_t)16 * 1024 * 1024;  // 16,777,216 per tensor
  f16* Qw = (f16*)d_ws;
  f16* Kw = Qw + ELEMS;
  f16* Vw = Kw + ELEMS;
  f16* Ow = Vw + ELEMS;  // 4 x 32MB = 128MB of workspace

  dim3 blk(256);
  gemm_tn<false, false><<<dim3(128, 8), blk, 0, stream>>>(x1, wq, wqb, Qw, 16384, 1024, 256);
  gemm_tn<false, false><<<dim3(128, 8), blk, 0, stream>>>(x2, wk, wkb, Kw, 16384, 1024, 256);
  gemm_tn<false, false><<<dim3(128, 8), blk, 0, stream>>>(x2, wv, wvb, Vw, 16384, 1024, 256);
  attn_fused<<<dim3(8, 128), blk, 0, stream>>>(Qw, Kw, Vw, Bm, Ow);
  gemm_tn<true, true><<<dim3(128, 1), blk, 0, stream>>>(Ow, pw, pb, out, 16384, 128, 1024);
}